// Round 9
// baseline (110.891 us; speedup 1.0000x reference)
//
#include <hip/hip_runtime.h>
#include <math.h>

// ================== problem constants ==================
#define BATCH   4096
#define NPUMP   4
#define NCH     100
#define RESPLEN 801

// RK4: 32 steps over 50 km (validated: absmax 1.22e-4 vs threshold 2.11e-4).
#define NSTEPS  32
#define DZ_F    1562.5f
#define HDZ_F   781.25f
#define DZ6_F   260.4166666666667f
#define LOSSC   4.605170185988092e-05f   // 0.0002 * ln(10)/10
#define INV256  0.00390625f              // undo the 2^8 G pre-scale

// ================== structure ==========================
// R9 = R8 (best: 58.2us rocprof) + critical-path micro-opts:
//  - pump dot2 restructured: 4 independent chains + tree (serial 16-chain
//    latency ~64cy -> ~28cy)
//  - s_setprio(1) on pump waves (0-3) across reads+pump: LDS pipe serves
//    the long-tail waves FIRST so their tails overlap the pure waves' drain
//  - tile epilogue reassociated: pump-coupling dot2 pair computed off the
//    MFMA-sum chain (fp32 reassoc only; << fp16 quantization noise)
// Base structure: 7 waves (448 thr), GB=16 (all 16 MFMA columns real),
// grid 256, wave w owns tile w; pump row 100+w in wave w (w<4) from its
// RESIDENT B-fragments + shfl_xor butterfly. 5 LDS reads/wave/stage.
#define GB      16
#define ROWSTR  136

typedef _Float16 f16;
typedef _Float16 f16x2 __attribute__((ext_vector_type(2)));
typedef _Float16 f16x8 __attribute__((ext_vector_type(8)));
typedef float    f32x4 __attribute__((ext_vector_type(4)));

union u8x { f16x8 v; f16x2 h[4]; };

#define MFMA16(Aa, Bb, Cc) __builtin_amdgcn_mfma_f32_16x16x32_f16((Aa), (Bb), (Cc), 0, 0, 0)
#define FDOT2(Aa, Bb, Cc)  __builtin_amdgcn_fdot2((Aa), (Bb), (Cc), false)

// Gain entry, scaled by 256 (3.2e12 = 1.25e10 * 2^8) so fp16-quantized
// near-diagonal entries stay normal. Consumers multiply y by INV256.
__device__ __forceinline__ float gentry(float fi, float fj, float invfj,
                                        const float* __restrict__ resp_s)
{
    float D    = fj - fi;
    float ad   = fabsf(D);
    float fidx = ad * 2.0e-11f;          // 1/DF
    int   i0   = (int)fidx;
    i0 = i0 > (RESPLEN - 2) ? (RESPLEN - 2) : i0;
    float w  = fidx - (float)i0;
    float g  = resp_s[i0] * (1.0f - w) + resp_s[i0 + 1] * w;
    g = (D < 0.0f) ? -g : g;
    float ratio = fi * invfj;
    float m  = fmaxf(1.0f, ratio);
    return g * m * 3.2e12f;              // (1/EFFECTIVE_AREA) * 256
}

// One RK stage. Reads P (fp16) from Pls[buf], writes next-stage P to
// Pls[buf^1], one barrier. FIRST_/LAST_ are 0/1 literals.
#define STAGE(A_, W_, FIRST_, LAST_)                                           \
  {                                                                            \
    if (wid < 4) __builtin_amdgcn_s_setprio(1);                                \
    const f16* pb = (const f16*)&Pls[buf][c][0];                               \
    u8x Bu0, Bu1, Bu2, Bu3;                                                    \
    Bu0.v = *(const f16x8*)(pb + 8 * q);                                       \
    Bu1.v = *(const f16x8*)(pb + 32 + 8 * q);                                  \
    Bu2.v = *(const f16x8*)(pb + 64 + 8 * q);                                  \
    Bu3.v = *(const f16x8*)(pb + 96 + 8 * q);                                  \
    union { uint2 u2; f16x2 h[2]; } ppu;                                       \
    ppu.u2 = *(const uint2*)(pb + 100);                                        \
    /* MFMAs first: matrix pipe runs under the pump VALU below */              \
    f32x4 a01 = {0.f,0.f,0.f,0.f}, a23 = {0.f,0.f,0.f,0.f};                    \
    a01 = MFMA16(Af[0], Bu0.v, a01);                                           \
    a23 = MFMA16(Af[1], Bu1.v, a23);                                           \
    a01 = MFMA16(Af[2], Bu2.v, a01);                                           \
    a23 = MFMA16(Af[3], Bu3.v, a23);                                           \
    if (wid < 4) { /* pump row 100+wid: 4 parallel chains + tree */            \
      float s00 = 0.0f, s01 = 0.0f, s02 = 0.0f, s03 = 0.0f;                    \
      _Pragma("unroll")                                                        \
      for (int jj = 0; jj < 4; ++jj) {                                         \
        s00 = FDOT2(gq[jj],      Bu0.h[jj], s00);                              \
        s01 = FDOT2(gq[4 + jj],  Bu1.h[jj], s01);                              \
        s02 = FDOT2(gq[8 + jj],  Bu2.h[jj], s02);                              \
        s03 = FDOT2(gq[12 + jj], Bu3.h[jj], s03);                              \
      }                                                                        \
      float s0 = (s00 + s01) + (s02 + s03);                                    \
      s0 += __shfl_xor(s0, 16);                                                \
      s0 += __shfl_xor(s0, 32);                                                \
      float kp = fmaf(s0, INV256, -LOSSC) * sp;                                \
      if (FIRST_) kps = kp; else kps += (W_) * kp;                             \
      if (LAST_) { P0p += DZ6_F * kps; sp = P0p; }                             \
      else       { sp = fmaf((A_), kp, P0p); }                                 \
      if (q == 0) Pls[buf ^ 1][c][NCH + wid] = (f16)sp;                        \
      __builtin_amdgcn_s_setprio(0);                                           \
    }                                                                          \
    { /* tile epilogue (rows row0..row0+3) */                                  \
      _Pragma("unroll")                                                        \
      for (int m = 0; m < 4; ++m) {                                            \
        float d = FDOT2(gp23[m], ppu.h[1], FDOT2(gp01[m], ppu.h[0], 0.0f));    \
        float y = (a01[m] + a23[m]) + d;                                       \
        float kk = fmaf(y, INV256, -LOSSC) * sv[m];                            \
        if (FIRST_) ks[m] = kk; else ks[m] += (W_) * kk;                       \
        if (LAST_) { P0v[m] += DZ6_F * ks[m]; sv[m] = P0v[m]; }                \
        else       { sv[m] = fmaf((A_), kk, P0v[m]); }                         \
      }                                                                        \
      if (row0 < NCH) {                                                        \
        union { f16x2 h[2]; uint2 u2; } cv;                                    \
        cv.h[0] = f16x2{(f16)sv[0], (f16)sv[1]};                               \
        cv.h[1] = f16x2{(f16)sv[2], (f16)sv[3]};                               \
        *(uint2*)&Pls[buf ^ 1][c][row0] = cv.u2;                               \
      }                                                                        \
    }                                                                          \
    __syncthreads();                                                           \
    buf ^= 1;                                                                  \
  }

__global__ __launch_bounds__(448)
void raman_kernel(const float* __restrict__ x,       // (BATCH, 8)
                  const float* __restrict__ resp,    // (801,)
                  const float* __restrict__ sigwl,   // (100,)
                  float* __restrict__ out)           // (BATCH, 100)
{
    // P: rows 0..99 = signal channels, 100..103 = pumps, 104..135 = zero pad
    __shared__ __align__(16) f16 Pls[2][GB][ROWSTR];
    __shared__ float resp_s[RESPLEN + 3];
    __shared__ float sigf[NCH], siginv[NCH];
    __shared__ float pf[GB][NPUMP], pinv[GB][NPUMP], ppw[GB][NPUMP];

    const int tid  = threadIdx.x;
    const int wid  = tid >> 6;    // 0..6 (wave = tile)
    const int lane = tid & 63;
    const int c    = lane & 15;   // MFMA column = batch within group
    const int q    = lane >> 4;   // quad index (k-group / C-row-group)
    const int b0   = blockIdx.x * GB;
    const int row0 = 16 * wid + 4 * q;   // C rows row0..row0+3

    for (int i = tid; i < RESPLEN; i += 448) resp_s[i] = resp[i];
    for (int i = tid; i < NCH; i += 448) {
        float lam = sigwl[i];
        sigf[i]   = 299792458.0f / lam;
        siginv[i] = lam * 3.3356409519815204e-09f;   // lam/C0
    }
    if (tid < GB * NPUMP) {
        const int cc = tid >> 2, p = tid & 3;
        float lam = x[(b0 + cc) * 8 + p];
        pf[cc][p]   = 299792458.0f / lam;
        pinv[cc][p] = lam * 3.3356409519815204e-09f;
        ppw[cc][p]  = fabsf(x[(b0 + cc) * 8 + NPUMP + p]);
    }
    {   // zero both P buffers (incl. pad rows; pads are never rewritten)
        f16* pz = (f16*)Pls;
        for (int i = tid; i < 2 * GB * ROWSTR; i += 448) pz[i] = (f16)0.0f;
    }
    __syncthreads();

    // ---- A fragments: shared signal-signal gain block (fp16, x256) ----
    // v_mfma_f32_16x16x32_f16: A[row][k]: row = lane%16, k = 8*(lane/16)+j
    // C/D: col = lane&15 (=batch c), row = 4*(lane>>4) + m
    f16x8 Af[4];
    f16x2 gp01[4], gp23[4];
    {
        const int arow = 16 * wid + c;
        const float fi = (arow < NCH) ? sigf[arow] : 0.0f;
        #pragma unroll
        for (int t = 0; t < 4; ++t) {
            f16x8 a;
            #pragma unroll
            for (int j = 0; j < 8; ++j) {
                const int k = 32 * t + 8 * q + j;
                float v = 0.0f;
                // pump columns (k>=100) excluded: added via gp01/gp23 dot2s
                if (arow < NCH && k < NCH)
                    v = gentry(fi, sigf[k], siginv[k], resp_s);
                a[j] = (f16)v;
            }
            Af[t] = a;
        }
        #pragma unroll
        for (int m = 0; m < 4; ++m) {
            const int row = row0 + m;
            float v0 = 0.f, v1 = 0.f, v2 = 0.f, v3 = 0.f;
            if (row < NCH) {
                const float fi2 = sigf[row];
                v0 = gentry(fi2, pf[c][0], pinv[c][0], resp_s);
                v1 = gentry(fi2, pf[c][1], pinv[c][1], resp_s);
                v2 = gentry(fi2, pf[c][2], pinv[c][2], resp_s);
                v3 = gentry(fi2, pf[c][3], pinv[c][3], resp_s);
            }
            gp01[m] = f16x2{(f16)v0, (f16)v1};
            gp23[m] = f16x2{(f16)v2, (f16)v3};
        }
    }

    // ---- pump-row gain slice (wid<4): wave wid owns pump row 100+wid.
    // gq[4u+jj] covers this lane's resident k = 32u + 8q + 2jj (+1).
    f16x2 gq[16];
    float P0p = 0.0f, sp = 0.0f, kps = 0.0f;
    if (wid < 4) {
        const float fi = pf[c][wid];
        #pragma unroll
        for (int u = 0; u < 4; ++u) {
            #pragma unroll
            for (int jj = 0; jj < 4; ++jj) {
                const int k0 = 32 * u + 8 * q + 2 * jj;
                const int k1 = k0 + 1;
                float g0 = 0.f, g1 = 0.f;
                if (k0 < NCH)
                    g0 = gentry(fi, sigf[k0], siginv[k0], resp_s);
                else if (k0 < NCH + NPUMP)
                    g0 = gentry(fi, pf[c][k0-NCH], pinv[c][k0-NCH], resp_s);
                if (k1 < NCH)
                    g1 = gentry(fi, sigf[k1], siginv[k1], resp_s);
                else if (k1 < NCH + NPUMP)
                    g1 = gentry(fi, pf[c][k1-NCH], pinv[c][k1-NCH], resp_s);
                gq[4 * u + jj] = f16x2{(f16)g0, (f16)g1};
            }
        }
        P0p = ppw[c][wid];
        sp  = P0p;
    }

    // ---- state init (f32, C-layout) + initial P into buffer 0 ----
    float P0v[4], sv[4], ks[4];
    #pragma unroll
    for (int m = 0; m < 4; ++m) {
        P0v[m] = (row0 + m < NCH) ? 1.0e-3f : 0.0f;
        sv[m]  = P0v[m];
        ks[m]  = 0.0f;
    }

    int buf = 0;
    if (row0 < NCH) {
        union { f16x2 h[2]; uint2 u2; } cv;
        cv.h[0] = f16x2{(f16)sv[0], (f16)sv[1]};
        cv.h[1] = f16x2{(f16)sv[2], (f16)sv[3]};
        *(uint2*)&Pls[0][c][row0] = cv.u2;
    }
    if (wid < 4 && q == 0) Pls[0][c][NCH + wid] = (f16)sp;
    __syncthreads();

    // ---- RK4 main loop: 32 steps x 4 stages, 1 barrier per stage ----
    #pragma unroll 1
    for (int step = 0; step < NSTEPS; ++step) {
        STAGE(HDZ_F, 1.0f, 1, 0)   // k1
        STAGE(HDZ_F, 2.0f, 0, 0)   // k2
        STAGE(DZ_F,  2.0f, 0, 0)   // k3
        STAGE(0.0f,  1.0f, 0, 1)   // k4 + P0 += dz/6 * ksum
    }

    // ---- output: signal rows 0..99 (float4, 16B-aligned: 400 = 25*16) ----
    if (row0 < NCH) {
        float4 o = make_float4(P0v[0], P0v[1], P0v[2], P0v[3]);
        *(float4*)&out[(b0 + c) * NCH + row0] = o;
    }
}

extern "C" void kernel_launch(void* const* d_in, const int* in_sizes, int n_in,
                              void* d_out, int out_size, void* d_ws, size_t ws_size,
                              hipStream_t stream)
{
    const float* x     = (const float*)d_in[0];
    const float* resp  = (const float*)d_in[1];
    const float* sigwl = (const float*)d_in[2];
    float* out = (float*)d_out;
    raman_kernel<<<BATCH / GB, 448, 0, stream>>>(x, resp, sigwl, out);
}

// Round 10
// 107.695 us; speedup vs baseline: 1.0297x; 1.0297x over previous
//
#include <hip/hip_runtime.h>
#include <math.h>

// ================== problem constants ==================
#define BATCH   4096
#define NPUMP   4
#define NCH     100
#define RESPLEN 801

// RK4: 32 steps over 50 km (validated: absmax 1.22e-4 vs threshold 2.11e-4).
#define NSTEPS  32
#define DZ_F    1562.5f
#define HDZ_F   781.25f
#define DZ6_F   260.4166666666667f
#define LOSSC   4.605170185988092e-05f   // 0.0002 * ln(10)/10
#define INV256  0.00390625f              // undo the 2^8 G pre-scale

// ================== structure ==========================
// R10 = R8 (best anchor: 58.2us rocprof; R9's setprio+reassoc reverted)
// + read-diet: K-chunk 3 (k=96..127, mostly pad) deleted. P[96..103]
// (tile-6 rows + pumps) is consumed via ONE b128 BROADCAST read (same
// address all lanes, conflict-free) + 4 dot2 per output row. This absorbs
// the old ppu b64 read too: per-wave reads 5 -> 4 (per-CU 35 -> 28, the
// DS-drain term is the stage bottleneck), MFMA per tile 4 -> 3.
// Base: 7 waves (448 thr), GB=16 (all MFMA columns real), grid 256,
// wave w owns tile w; pump row 100+w in wave w (w<4) from its RESIDENT
// B-fragments (12 dot2 + shfl_xor butterfly) + broadcast tail (4 dot2,
// added once after the butterfly == R8's q0-only chunk-3 contribution).
#define GB      16
#define ROWSTR  136

typedef _Float16 f16;
typedef _Float16 f16x2 __attribute__((ext_vector_type(2)));
typedef _Float16 f16x8 __attribute__((ext_vector_type(8)));
typedef float    f32x4 __attribute__((ext_vector_type(4)));

union u8x { f16x8 v; f16x2 h[4]; };

#define MFMA16(Aa, Bb, Cc) __builtin_amdgcn_mfma_f32_16x16x32_f16((Aa), (Bb), (Cc), 0, 0, 0)
#define FDOT2(Aa, Bb, Cc)  __builtin_amdgcn_fdot2((Aa), (Bb), (Cc), false)

// Gain entry, scaled by 256 (3.2e12 = 1.25e10 * 2^8) so fp16-quantized
// near-diagonal entries stay normal. Consumers multiply y by INV256.
__device__ __forceinline__ float gentry(float fi, float fj, float invfj,
                                        const float* __restrict__ resp_s)
{
    float D    = fj - fi;
    float ad   = fabsf(D);
    float fidx = ad * 2.0e-11f;          // 1/DF
    int   i0   = (int)fidx;
    i0 = i0 > (RESPLEN - 2) ? (RESPLEN - 2) : i0;
    float w  = fidx - (float)i0;
    float g  = resp_s[i0] * (1.0f - w) + resp_s[i0 + 1] * w;
    g = (D < 0.0f) ? -g : g;
    float ratio = fi * invfj;
    float m  = fmaxf(1.0f, ratio);
    return g * m * 3.2e12f;              // (1/EFFECTIVE_AREA) * 256
}

// One RK stage. Reads P (fp16) from Pls[buf], writes next-stage P to
// Pls[buf^1], one barrier. FIRST_/LAST_ are 0/1 literals.
#define STAGE(A_, W_, FIRST_, LAST_)                                           \
  {                                                                            \
    const f16* pb = (const f16*)&Pls[buf][c][0];                               \
    u8x Bu0, Bu1, Bu2, Tl;                                                     \
    Bu0.v = *(const f16x8*)(pb + 8 * q);                                       \
    Bu1.v = *(const f16x8*)(pb + 32 + 8 * q);                                  \
    Bu2.v = *(const f16x8*)(pb + 64 + 8 * q);                                  \
    Tl.v  = *(const f16x8*)(pb + 96);     /* broadcast: P[96..103] */          \
    /* MFMAs first: matrix pipe runs under the pump VALU below */              \
    f32x4 a01 = {0.f,0.f,0.f,0.f}, a23 = {0.f,0.f,0.f,0.f};                    \
    a01 = MFMA16(Af[0], Bu0.v, a01);                                           \
    a23 = MFMA16(Af[1], Bu1.v, a23);                                           \
    a01 = MFMA16(Af[2], Bu2.v, a01);                                           \
    if (wid < 4) { /* pump row 100+wid from resident B regs */                 \
      float s0 = 0.0f;                                                         \
      _Pragma("unroll")                                                        \
      for (int jj = 0; jj < 4; ++jj) {                                         \
        s0 = FDOT2(gq[jj],     Bu0.h[jj], s0);                                 \
        s0 = FDOT2(gq[4 + jj], Bu1.h[jj], s0);                                 \
        s0 = FDOT2(gq[8 + jj], Bu2.h[jj], s0);                                 \
      }                                                                        \
      float st = 0.0f;                                                         \
      _Pragma("unroll")                                                        \
      for (int t = 0; t < 4; ++t) st = FDOT2(gqt[t], Tl.h[t], st);             \
      s0 += __shfl_xor(s0, 16);                                                \
      s0 += __shfl_xor(s0, 32);                                                \
      float kp = fmaf(s0 + st, INV256, -LOSSC) * sp;                           \
      if (FIRST_) kps = kp; else kps += (W_) * kp;                             \
      if (LAST_) { P0p += DZ6_F * kps; sp = P0p; }                             \
      else       { sp = fmaf((A_), kp, P0p); }                                 \
      if (q == 0) Pls[buf ^ 1][c][NCH + wid] = (f16)sp;                        \
    }                                                                          \
    { /* tile epilogue (rows row0..row0+3) */                                  \
      _Pragma("unroll")                                                        \
      for (int m = 0; m < 4; ++m) {                                            \
        float y = a01[m] + a23[m];                                             \
        y = FDOT2(gpt[m][0], Tl.h[0], y);                                      \
        y = FDOT2(gpt[m][1], Tl.h[1], y);                                      \
        y = FDOT2(gpt[m][2], Tl.h[2], y);                                      \
        y = FDOT2(gpt[m][3], Tl.h[3], y);                                      \
        float kk = fmaf(y, INV256, -LOSSC) * sv[m];                            \
        if (FIRST_) ks[m] = kk; else ks[m] += (W_) * kk;                       \
        if (LAST_) { P0v[m] += DZ6_F * ks[m]; sv[m] = P0v[m]; }                \
        else       { sv[m] = fmaf((A_), kk, P0v[m]); }                         \
      }                                                                        \
      if (row0 < NCH) {                                                        \
        union { f16x2 h[2]; uint2 u2; } cv;                                    \
        cv.h[0] = f16x2{(f16)sv[0], (f16)sv[1]};                               \
        cv.h[1] = f16x2{(f16)sv[2], (f16)sv[3]};                               \
        *(uint2*)&Pls[buf ^ 1][c][row0] = cv.u2;                               \
      }                                                                        \
    }                                                                          \
    __syncthreads();                                                           \
    buf ^= 1;                                                                  \
  }

__global__ __launch_bounds__(448)
void raman_kernel(const float* __restrict__ x,       // (BATCH, 8)
                  const float* __restrict__ resp,    // (801,)
                  const float* __restrict__ sigwl,   // (100,)
                  float* __restrict__ out)           // (BATCH, 100)
{
    // P: rows 0..99 = signal channels, 100..103 = pumps, 104..135 = zero pad
    __shared__ __align__(16) f16 Pls[2][GB][ROWSTR];
    __shared__ float resp_s[RESPLEN + 3];
    __shared__ float sigf[NCH], siginv[NCH];
    __shared__ float pf[GB][NPUMP], pinv[GB][NPUMP], ppw[GB][NPUMP];

    const int tid  = threadIdx.x;
    const int wid  = tid >> 6;    // 0..6 (wave = tile)
    const int lane = tid & 63;
    const int c    = lane & 15;   // MFMA column = batch within group
    const int q    = lane >> 4;   // quad index (k-group / C-row-group)
    const int b0   = blockIdx.x * GB;
    const int row0 = 16 * wid + 4 * q;   // C rows row0..row0+3

    for (int i = tid; i < RESPLEN; i += 448) resp_s[i] = resp[i];
    for (int i = tid; i < NCH; i += 448) {
        float lam = sigwl[i];
        sigf[i]   = 299792458.0f / lam;
        siginv[i] = lam * 3.3356409519815204e-09f;   // lam/C0
    }
    if (tid < GB * NPUMP) {
        const int cc = tid >> 2, p = tid & 3;
        float lam = x[(b0 + cc) * 8 + p];
        pf[cc][p]   = 299792458.0f / lam;
        pinv[cc][p] = lam * 3.3356409519815204e-09f;
        ppw[cc][p]  = fabsf(x[(b0 + cc) * 8 + NPUMP + p]);
    }
    {   // zero both P buffers (incl. pad rows; pads are never rewritten)
        f16* pz = (f16*)Pls;
        for (int i = tid; i < 2 * GB * ROWSTR; i += 448) pz[i] = (f16)0.0f;
    }
    __syncthreads();

    // ---- A fragments: shared signal-signal gain block (fp16, x256) ----
    // Only K-chunks 0..2 (k=0..95); k=96..103 handled via gpt/gqt dot2s.
    // v_mfma_f32_16x16x32_f16: A[row][k]: row = lane%16, k = 8*(lane/16)+j
    // C/D: col = lane&15 (=batch c), row = 4*(lane>>4) + m
    f16x8 Af[3];
    f16x2 gpt[4][4];
    {
        const int arow = 16 * wid + c;
        const float fi = (arow < NCH) ? sigf[arow] : 0.0f;
        #pragma unroll
        for (int t = 0; t < 3; ++t) {
            f16x8 a;
            #pragma unroll
            for (int j = 0; j < 8; ++j) {
                const int k = 32 * t + 8 * q + j;   // k <= 95 < NCH
                float v = 0.0f;
                if (arow < NCH)
                    v = gentry(fi, sigf[k], siginv[k], resp_s);
                a[j] = (f16)v;
            }
            Af[t] = a;
        }
        // gpt[m][t]: G[row][96+2t], G[row][97+2t] — signal cols 96..99
        // (shared) + pump cols 100..103 (batch-specific)
        #pragma unroll
        for (int m = 0; m < 4; ++m) {
            const int row = row0 + m;
            #pragma unroll
            for (int t = 0; t < 4; ++t) {
                const int j0 = 96 + 2 * t, j1 = 97 + 2 * t;
                float v0 = 0.f, v1 = 0.f;
                if (row < NCH) {
                    const float fi2 = sigf[row];
                    v0 = (j0 < NCH)
                       ? gentry(fi2, sigf[j0], siginv[j0], resp_s)
                       : gentry(fi2, pf[c][j0-NCH], pinv[c][j0-NCH], resp_s);
                    v1 = (j1 < NCH)
                       ? gentry(fi2, sigf[j1], siginv[j1], resp_s)
                       : gentry(fi2, pf[c][j1-NCH], pinv[c][j1-NCH], resp_s);
                }
                gpt[m][t] = f16x2{(f16)v0, (f16)v1};
            }
        }
    }

    // ---- pump-row gain slices (wid<4): wave wid owns pump row 100+wid.
    // gq[4u+jj]: lane's resident k = 32u + 8q + 2jj (+1), u<3 (k<96).
    // gqt[t]: broadcast tail k = 96+2t (+1), uniform across q.
    f16x2 gq[12], gqt[4];
    float P0p = 0.0f, sp = 0.0f, kps = 0.0f;
    if (wid < 4) {
        const float fi = pf[c][wid];
        #pragma unroll
        for (int u = 0; u < 3; ++u) {
            #pragma unroll
            for (int jj = 0; jj < 4; ++jj) {
                const int k0 = 32 * u + 8 * q + 2 * jj;   // < 96
                const int k1 = k0 + 1;
                gq[4 * u + jj] =
                    f16x2{(f16)gentry(fi, sigf[k0], siginv[k0], resp_s),
                          (f16)gentry(fi, sigf[k1], siginv[k1], resp_s)};
            }
        }
        #pragma unroll
        for (int t = 0; t < 4; ++t) {
            const int j0 = 96 + 2 * t, j1 = 97 + 2 * t;
            float g0 = (j0 < NCH)
                     ? gentry(fi, sigf[j0], siginv[j0], resp_s)
                     : gentry(fi, pf[c][j0-NCH], pinv[c][j0-NCH], resp_s);
            float g1 = (j1 < NCH)
                     ? gentry(fi, sigf[j1], siginv[j1], resp_s)
                     : gentry(fi, pf[c][j1-NCH], pinv[c][j1-NCH], resp_s);
            gqt[t] = f16x2{(f16)g0, (f16)g1};
        }
        P0p = ppw[c][wid];
        sp  = P0p;
    }

    // ---- state init (f32, C-layout) + initial P into buffer 0 ----
    float P0v[4], sv[4], ks[4];
    #pragma unroll
    for (int m = 0; m < 4; ++m) {
        P0v[m] = (row0 + m < NCH) ? 1.0e-3f : 0.0f;
        sv[m]  = P0v[m];
        ks[m]  = 0.0f;
    }

    int buf = 0;
    if (row0 < NCH) {
        union { f16x2 h[2]; uint2 u2; } cv;
        cv.h[0] = f16x2{(f16)sv[0], (f16)sv[1]};
        cv.h[1] = f16x2{(f16)sv[2], (f16)sv[3]};
        *(uint2*)&Pls[0][c][row0] = cv.u2;
    }
    if (wid < 4 && q == 0) Pls[0][c][NCH + wid] = (f16)sp;
    __syncthreads();

    // ---- RK4 main loop: 32 steps x 4 stages, 1 barrier per stage ----
    #pragma unroll 1
    for (int step = 0; step < NSTEPS; ++step) {
        STAGE(HDZ_F, 1.0f, 1, 0)   // k1
        STAGE(HDZ_F, 2.0f, 0, 0)   // k2
        STAGE(DZ_F,  2.0f, 0, 0)   // k3
        STAGE(0.0f,  1.0f, 0, 1)   // k4 + P0 += dz/6 * ksum
    }

    // ---- output: signal rows 0..99 (float4, 16B-aligned: 400 = 25*16) ----
    if (row0 < NCH) {
        float4 o = make_float4(P0v[0], P0v[1], P0v[2], P0v[3]);
        *(float4*)&out[(b0 + c) * NCH + row0] = o;
    }
}

extern "C" void kernel_launch(void* const* d_in, const int* in_sizes, int n_in,
                              void* d_out, int out_size, void* d_ws, size_t ws_size,
                              hipStream_t stream)
{
    const float* x     = (const float*)d_in[0];
    const float* resp  = (const float*)d_in[1];
    const float* sigwl = (const float*)d_in[2];
    float* out = (float*)d_out;
    raman_kernel<<<BATCH / GB, 448, 0, stream>>>(x, resp, sigwl, out);
}

// Round 11
// 105.490 us; speedup vs baseline: 1.0512x; 1.0209x over previous
//
#include <hip/hip_runtime.h>
#include <math.h>

// ================== problem constants ==================
#define BATCH   4096
#define NPUMP   4
#define NCH     100
#define RESPLEN 801

// RK4: 32 steps over 50 km (validated: absmax 1.22e-4 vs threshold 2.11e-4).
#define NSTEPS  32
#define DZ_F    1562.5f
#define HDZ_F   781.25f
#define DZ6_F   260.4166666666667f
#define LOSSC   4.605170185988092e-05f   // 0.0002 * ln(10)/10
#define INV256  0.00390625f              // undo the 2^8 G pre-scale

// ================== structure ==========================
// R11 = R10 + ONE change: the pump-wave cross-lane reduction
// (shfl_xor 16/32 = ds_swizzle/ds_permute, LDS-pipe, ~100cy each, serial
// on the slowest wave's critical path) is replaced by gfx950 VALU
// cross-lane ops v_permlane16_swap_b32 + v_permlane32_swap_b32 (~4-8cy).
// Association is bit-identical: (s0+s16)+(s32+s48), valid on lanes 0-15
// (q=0) which are the only consumers. __has_builtin-guarded; fallback
// compiles to exactly R10.
// Base: 7 waves (448 thr), GB=16, grid 256. Wave w owns tile w; K-chunks
// 0..2 via MFMA + P[96..103] broadcast-read tail via dot2. Pump row
// 100+w in wave w (w<4) from resident B-fragments.
#define GB      16
#define ROWSTR  136

typedef _Float16 f16;
typedef _Float16 f16x2 __attribute__((ext_vector_type(2)));
typedef _Float16 f16x8 __attribute__((ext_vector_type(8)));
typedef float    f32x4 __attribute__((ext_vector_type(4)));
typedef unsigned uint2v __attribute__((ext_vector_type(2)));

union u8x { f16x8 v; f16x2 h[4]; };

#define MFMA16(Aa, Bb, Cc) __builtin_amdgcn_mfma_f32_16x16x32_f16((Aa), (Bb), (Cc), 0, 0, 0)
#define FDOT2(Aa, Bb, Cc)  __builtin_amdgcn_fdot2((Aa), (Bb), (Cc), false)

// Cross-q reduction: lanes 0-15 end with s(q0)+s(q1)+s(q2)+s(q3).
// Same association as the shfl_xor version: (s+s^16) + ((s^32)+(s^48)).
__device__ __forceinline__ float pump_reduce(float s)
{
#if __has_builtin(__builtin_amdgcn_permlane16_swap) && \
    __has_builtin(__builtin_amdgcn_permlane32_swap)
    union { float f; unsigned u; } a, b, t;
    a.f = s;
    // new vsrc[i] = old vdst[i+16] for i in [0,16)+[32,48): partner s^16
    uint2v r1 = __builtin_amdgcn_permlane16_swap(a.u, a.u, false, false);
    t.u = r1[1];
    float s2 = s + t.f;                  // lanes 0-15 & 32-47: s + s^16
    b.f = s2;
    // new vsrc[i] = old vdst[i+32] for i in [0,32): partner s2^32
    uint2v r2 = __builtin_amdgcn_permlane32_swap(b.u, b.u, false, false);
    t.u = r2[1];
    return s2 + t.f;                     // lanes 0-15: full sum
#else
    s += __shfl_xor(s, 16);
    s += __shfl_xor(s, 32);
    return s;
#endif
}

// Gain entry, scaled by 256 (3.2e12 = 1.25e10 * 2^8) so fp16-quantized
// near-diagonal entries stay normal. Consumers multiply y by INV256.
__device__ __forceinline__ float gentry(float fi, float fj, float invfj,
                                        const float* __restrict__ resp_s)
{
    float D    = fj - fi;
    float ad   = fabsf(D);
    float fidx = ad * 2.0e-11f;          // 1/DF
    int   i0   = (int)fidx;
    i0 = i0 > (RESPLEN - 2) ? (RESPLEN - 2) : i0;
    float w  = fidx - (float)i0;
    float g  = resp_s[i0] * (1.0f - w) + resp_s[i0 + 1] * w;
    g = (D < 0.0f) ? -g : g;
    float ratio = fi * invfj;
    float m  = fmaxf(1.0f, ratio);
    return g * m * 3.2e12f;              // (1/EFFECTIVE_AREA) * 256
}

// One RK stage. Reads P (fp16) from Pls[buf], writes next-stage P to
// Pls[buf^1], one barrier. FIRST_/LAST_ are 0/1 literals.
#define STAGE(A_, W_, FIRST_, LAST_)                                           \
  {                                                                            \
    const f16* pb = (const f16*)&Pls[buf][c][0];                               \
    u8x Bu0, Bu1, Bu2, Tl;                                                     \
    Bu0.v = *(const f16x8*)(pb + 8 * q);                                       \
    Bu1.v = *(const f16x8*)(pb + 32 + 8 * q);                                  \
    Bu2.v = *(const f16x8*)(pb + 64 + 8 * q);                                  \
    Tl.v  = *(const f16x8*)(pb + 96);     /* broadcast: P[96..103] */          \
    /* MFMAs first: matrix pipe runs under the pump VALU below */              \
    f32x4 a01 = {0.f,0.f,0.f,0.f}, a23 = {0.f,0.f,0.f,0.f};                    \
    a01 = MFMA16(Af[0], Bu0.v, a01);                                           \
    a23 = MFMA16(Af[1], Bu1.v, a23);                                           \
    a01 = MFMA16(Af[2], Bu2.v, a01);                                           \
    if (wid < 4) { /* pump row 100+wid from resident B regs */                 \
      float s0 = 0.0f;                                                         \
      _Pragma("unroll")                                                        \
      for (int jj = 0; jj < 4; ++jj) {                                         \
        s0 = FDOT2(gq[jj],     Bu0.h[jj], s0);                                 \
        s0 = FDOT2(gq[4 + jj], Bu1.h[jj], s0);                                 \
        s0 = FDOT2(gq[8 + jj], Bu2.h[jj], s0);                                 \
      }                                                                        \
      float st = 0.0f;                                                         \
      _Pragma("unroll")                                                        \
      for (int t = 0; t < 4; ++t) st = FDOT2(gqt[t], Tl.h[t], st);             \
      s0 = pump_reduce(s0);                                                    \
      float kp = fmaf(s0 + st, INV256, -LOSSC) * sp;                           \
      if (FIRST_) kps = kp; else kps += (W_) * kp;                             \
      if (LAST_) { P0p += DZ6_F * kps; sp = P0p; }                             \
      else       { sp = fmaf((A_), kp, P0p); }                                 \
      if (q == 0) Pls[buf ^ 1][c][NCH + wid] = (f16)sp;                        \
    }                                                                          \
    { /* tile epilogue (rows row0..row0+3) */                                  \
      _Pragma("unroll")                                                        \
      for (int m = 0; m < 4; ++m) {                                            \
        float y = a01[m] + a23[m];                                             \
        y = FDOT2(gpt[m][0], Tl.h[0], y);                                      \
        y = FDOT2(gpt[m][1], Tl.h[1], y);                                      \
        y = FDOT2(gpt[m][2], Tl.h[2], y);                                      \
        y = FDOT2(gpt[m][3], Tl.h[3], y);                                      \
        float kk = fmaf(y, INV256, -LOSSC) * sv[m];                            \
        if (FIRST_) ks[m] = kk; else ks[m] += (W_) * kk;                       \
        if (LAST_) { P0v[m] += DZ6_F * ks[m]; sv[m] = P0v[m]; }                \
        else       { sv[m] = fmaf((A_), kk, P0v[m]); }                         \
      }                                                                        \
      if (row0 < NCH) {                                                        \
        union { f16x2 h[2]; uint2 u2; } cv;                                    \
        cv.h[0] = f16x2{(f16)sv[0], (f16)sv[1]};                               \
        cv.h[1] = f16x2{(f16)sv[2], (f16)sv[3]};                               \
        *(uint2*)&Pls[buf ^ 1][c][row0] = cv.u2;                               \
      }                                                                        \
    }                                                                          \
    __syncthreads();                                                           \
    buf ^= 1;                                                                  \
  }

__global__ __launch_bounds__(448)
void raman_kernel(const float* __restrict__ x,       // (BATCH, 8)
                  const float* __restrict__ resp,    // (801,)
                  const float* __restrict__ sigwl,   // (100,)
                  float* __restrict__ out)           // (BATCH, 100)
{
    // P: rows 0..99 = signal channels, 100..103 = pumps, 104..135 = zero pad
    __shared__ __align__(16) f16 Pls[2][GB][ROWSTR];
    __shared__ float resp_s[RESPLEN + 3];
    __shared__ float sigf[NCH], siginv[NCH];
    __shared__ float pf[GB][NPUMP], pinv[GB][NPUMP], ppw[GB][NPUMP];

    const int tid  = threadIdx.x;
    const int wid  = tid >> 6;    // 0..6 (wave = tile)
    const int lane = tid & 63;
    const int c    = lane & 15;   // MFMA column = batch within group
    const int q    = lane >> 4;   // quad index (k-group / C-row-group)
    const int b0   = blockIdx.x * GB;
    const int row0 = 16 * wid + 4 * q;   // C rows row0..row0+3

    for (int i = tid; i < RESPLEN; i += 448) resp_s[i] = resp[i];
    for (int i = tid; i < NCH; i += 448) {
        float lam = sigwl[i];
        sigf[i]   = 299792458.0f / lam;
        siginv[i] = lam * 3.3356409519815204e-09f;   // lam/C0
    }
    if (tid < GB * NPUMP) {
        const int cc = tid >> 2, p = tid & 3;
        float lam = x[(b0 + cc) * 8 + p];
        pf[cc][p]   = 299792458.0f / lam;
        pinv[cc][p] = lam * 3.3356409519815204e-09f;
        ppw[cc][p]  = fabsf(x[(b0 + cc) * 8 + NPUMP + p]);
    }
    {   // zero both P buffers (incl. pad rows; pads are never rewritten)
        f16* pz = (f16*)Pls;
        for (int i = tid; i < 2 * GB * ROWSTR; i += 448) pz[i] = (f16)0.0f;
    }
    __syncthreads();

    // ---- A fragments: shared signal-signal gain block (fp16, x256) ----
    // Only K-chunks 0..2 (k=0..95); k=96..103 handled via gpt/gqt dot2s.
    // v_mfma_f32_16x16x32_f16: A[row][k]: row = lane%16, k = 8*(lane/16)+j
    // C/D: col = lane&15 (=batch c), row = 4*(lane>>4) + m
    f16x8 Af[3];
    f16x2 gpt[4][4];
    {
        const int arow = 16 * wid + c;
        const float fi = (arow < NCH) ? sigf[arow] : 0.0f;
        #pragma unroll
        for (int t = 0; t < 3; ++t) {
            f16x8 a;
            #pragma unroll
            for (int j = 0; j < 8; ++j) {
                const int k = 32 * t + 8 * q + j;   // k <= 95 < NCH
                float v = 0.0f;
                if (arow < NCH)
                    v = gentry(fi, sigf[k], siginv[k], resp_s);
                a[j] = (f16)v;
            }
            Af[t] = a;
        }
        // gpt[m][t]: G[row][96+2t], G[row][97+2t] — signal cols 96..99
        // (shared) + pump cols 100..103 (batch-specific)
        #pragma unroll
        for (int m = 0; m < 4; ++m) {
            const int row = row0 + m;
            #pragma unroll
            for (int t = 0; t < 4; ++t) {
                const int j0 = 96 + 2 * t, j1 = 97 + 2 * t;
                float v0 = 0.f, v1 = 0.f;
                if (row < NCH) {
                    const float fi2 = sigf[row];
                    v0 = (j0 < NCH)
                       ? gentry(fi2, sigf[j0], siginv[j0], resp_s)
                       : gentry(fi2, pf[c][j0-NCH], pinv[c][j0-NCH], resp_s);
                    v1 = (j1 < NCH)
                       ? gentry(fi2, sigf[j1], siginv[j1], resp_s)
                       : gentry(fi2, pf[c][j1-NCH], pinv[c][j1-NCH], resp_s);
                }
                gpt[m][t] = f16x2{(f16)v0, (f16)v1};
            }
        }
    }

    // ---- pump-row gain slices (wid<4): wave wid owns pump row 100+wid.
    // gq[4u+jj]: lane's resident k = 32u + 8q + 2jj (+1), u<3 (k<96).
    // gqt[t]: broadcast tail k = 96+2t (+1), uniform across q.
    f16x2 gq[12], gqt[4];
    float P0p = 0.0f, sp = 0.0f, kps = 0.0f;
    if (wid < 4) {
        const float fi = pf[c][wid];
        #pragma unroll
        for (int u = 0; u < 3; ++u) {
            #pragma unroll
            for (int jj = 0; jj < 4; ++jj) {
                const int k0 = 32 * u + 8 * q + 2 * jj;   // < 96
                const int k1 = k0 + 1;
                gq[4 * u + jj] =
                    f16x2{(f16)gentry(fi, sigf[k0], siginv[k0], resp_s),
                          (f16)gentry(fi, sigf[k1], siginv[k1], resp_s)};
            }
        }
        #pragma unroll
        for (int t = 0; t < 4; ++t) {
            const int j0 = 96 + 2 * t, j1 = 97 + 2 * t;
            float g0 = (j0 < NCH)
                     ? gentry(fi, sigf[j0], siginv[j0], resp_s)
                     : gentry(fi, pf[c][j0-NCH], pinv[c][j0-NCH], resp_s);
            float g1 = (j1 < NCH)
                     ? gentry(fi, sigf[j1], siginv[j1], resp_s)
                     : gentry(fi, pf[c][j1-NCH], pinv[c][j1-NCH], resp_s);
            gqt[t] = f16x2{(f16)g0, (f16)g1};
        }
        P0p = ppw[c][wid];
        sp  = P0p;
    }

    // ---- state init (f32, C-layout) + initial P into buffer 0 ----
    float P0v[4], sv[4], ks[4];
    #pragma unroll
    for (int m = 0; m < 4; ++m) {
        P0v[m] = (row0 + m < NCH) ? 1.0e-3f : 0.0f;
        sv[m]  = P0v[m];
        ks[m]  = 0.0f;
    }

    int buf = 0;
    if (row0 < NCH) {
        union { f16x2 h[2]; uint2 u2; } cv;
        cv.h[0] = f16x2{(f16)sv[0], (f16)sv[1]};
        cv.h[1] = f16x2{(f16)sv[2], (f16)sv[3]};
        *(uint2*)&Pls[0][c][row0] = cv.u2;
    }
    if (wid < 4 && q == 0) Pls[0][c][NCH + wid] = (f16)sp;
    __syncthreads();

    // ---- RK4 main loop: 32 steps x 4 stages, 1 barrier per stage ----
    #pragma unroll 1
    for (int step = 0; step < NSTEPS; ++step) {
        STAGE(HDZ_F, 1.0f, 1, 0)   // k1
        STAGE(HDZ_F, 2.0f, 0, 0)   // k2
        STAGE(DZ_F,  2.0f, 0, 0)   // k3
        STAGE(0.0f,  1.0f, 0, 1)   // k4 + P0 += dz/6 * ksum
    }

    // ---- output: signal rows 0..99 (float4, 16B-aligned: 400 = 25*16) ----
    if (row0 < NCH) {
        float4 o = make_float4(P0v[0], P0v[1], P0v[2], P0v[3]);
        *(float4*)&out[(b0 + c) * NCH + row0] = o;
    }
}

extern "C" void kernel_launch(void* const* d_in, const int* in_sizes, int n_in,
                              void* d_out, int out_size, void* d_ws, size_t ws_size,
                              hipStream_t stream)
{
    const float* x     = (const float*)d_in[0];
    const float* resp  = (const float*)d_in[1];
    const float* sigwl = (const float*)d_in[2];
    float* out = (float*)d_out;
    raman_kernel<<<BATCH / GB, 448, 0, stream>>>(x, resp, sigwl, out);
}